// Round 4
// baseline (457.593 us; speedup 1.0000x reference)
//
#include <hip/hip_runtime.h>
#include <hip/hip_fp16.h>
#include <math.h>

#define NN 50000
#define EE 800000
#define FIN 128
#define F1  128   // HEADS*HID
#define NH  8
#define DH  16
#define F2  32
#define SLOPE 0.2f
#define LOG2E 1.44269504f

// ---------------- CSR build ----------------
__global__ void degree_kernel(const int* __restrict__ dst, int* __restrict__ deg) {
    int i = blockIdx.x * 256 + threadIdx.x;
    if (i < EE) atomicAdd(&deg[dst[i]], 1);
}

__global__ void partial_sum_kernel(const int* __restrict__ deg, int* __restrict__ partials) {
    __shared__ int sh[256];
    int i = blockIdx.x * 256 + threadIdx.x;
    sh[threadIdx.x] = (i < NN) ? deg[i] : 0;
    __syncthreads();
    for (int off = 128; off > 0; off >>= 1) {
        if (threadIdx.x < off) sh[threadIdx.x] += sh[threadIdx.x + off];
        __syncthreads();
    }
    if (threadIdx.x == 0) partials[blockIdx.x] = sh[0];
}

// single-wave shuffle scan over up to 256 block partials
__global__ void scan_partials_kernel(const int* __restrict__ partials, int* __restrict__ pscan, int nblk) {
    int lane = threadIdx.x;   // 64 lanes, lane i owns indices [4i, 4i+4)
    int v[4], e[4];
    #pragma unroll
    for (int j = 0; j < 4; ++j) {
        int idx = lane * 4 + j;
        v[j] = (idx < nblk) ? partials[idx] : 0;
    }
    e[0] = 0; e[1] = v[0]; e[2] = v[0] + v[1]; e[3] = e[2] + v[2];
    int tot = e[3] + v[3];
    int inc = tot;
    #pragma unroll
    for (int off = 1; off < 64; off <<= 1) {
        int u = __shfl_up(inc, off, 64);
        if (lane >= off) inc += u;
    }
    int base = inc - tot;   // exclusive prefix of lane totals
    #pragma unroll
    for (int j = 0; j < 4; ++j) {
        int idx = lane * 4 + j;
        if (idx < nblk) pscan[idx] = base + e[j];
    }
}

__global__ void scan_kernel(const int* __restrict__ deg, const int* __restrict__ pscan,
                            int* __restrict__ row_ptr) {
    __shared__ int sh[256];
    int tid = threadIdx.x;
    int i = blockIdx.x * 256 + tid;
    int v = (i < NN) ? deg[i] : 0;
    sh[tid] = v;
    __syncthreads();
    for (int off = 1; off < 256; off <<= 1) {
        int t = (tid >= off) ? sh[tid - off] : 0;
        __syncthreads();
        sh[tid] += t;
        __syncthreads();
    }
    if (i < NN) row_ptr[i] = pscan[blockIdx.x] + sh[tid] - v;
    if (i == 0) row_ptr[NN] = EE;
}

__global__ void scatter_kernel(const int* __restrict__ src, const int* __restrict__ dst,
                               const int* __restrict__ row_ptr, int* __restrict__ fill,
                               int* __restrict__ csr_src) {
    int i = blockIdx.x * 256 + threadIdx.x;
    if (i < EE) {
        int d = dst[i];
        int pos = row_ptr[d] + atomicAdd(&fill[d], 1);
        csr_src[pos] = src[i];
    }
}

// ---------------- GEMM1 + es/ed epilogue ----------------
// Weight-stationary: thread owns W1 column c (128 VGPRs). h rows staged in LDS,
// read as same-address b128 broadcasts (conflict-free). tid&127 = col,
// tid>>7 = row-half (wave-uniform). Emits fp16 z1h + exp2-scaled es1x/ed1x.
__global__ __launch_bounds__(256) void gemm1es_kernel(const float* __restrict__ h,
        const float* __restrict__ W, const float* __restrict__ a1s, const float* __restrict__ a1d,
        __half* __restrict__ z1h, float* __restrict__ es1x, float* __restrict__ ed1x) {
    __shared__ float hbuf[32 * FIN];   // 16 KB
    int tid = threadIdx.x;
    int c = tid & 127, rh = tid >> 7;
    float w[128];
    #pragma unroll
    for (int kk = 0; kk < 128; ++kk) w[kk] = W[kk * F1 + c];
    float as = a1s[c], ad = a1d[c];
    int rowBase = blockIdx.x * 32;
    for (int idx = tid * 4; idx < 32 * FIN; idx += 1024) {
        int r = idx >> 7, k = idx & 127;
        int n = rowBase + r;
        float4 v = (n < NN) ? *(const float4*)&h[(size_t)n * FIN + k] : make_float4(0, 0, 0, 0);
        *(float4*)&hbuf[idx] = v;
    }
    __syncthreads();
    #pragma unroll
    for (int b = 0; b < 4; ++b) {
        int r0 = rh * 16 + b * 4;
        float acc[4] = {0.f, 0.f, 0.f, 0.f};
        #pragma unroll
        for (int k = 0; k < 128; k += 4) {
            #pragma unroll
            for (int rr = 0; rr < 4; ++rr) {
                float4 hv = *(float4*)&hbuf[(r0 + rr) * FIN + k];
                acc[rr] = fmaf(hv.x, w[k], fmaf(hv.y, w[k+1], fmaf(hv.z, w[k+2], fmaf(hv.w, w[k+3], acc[rr]))));
            }
        }
        #pragma unroll
        for (int rr = 0; rr < 4; ++rr) {
            int row = rowBase + r0 + rr;
            float z = acc[rr];
            float s = z * as, d = z * ad;
            #pragma unroll
            for (int o = 1; o < 16; o <<= 1) { s += __shfl_xor(s, o, 64); d += __shfl_xor(d, o, 64); }
            if (row < NN) {
                z1h[(size_t)row * F1 + c] = __float2half(z);
                if ((c & 15) == 0) {
                    es1x[row * NH + (c >> 4)] = s * LOG2E;
                    ed1x[row * NH + (c >> 4)] = d * LOG2E;
                }
            }
        }
    }
}

// ---------------- GEMM2 + es/ed epilogue ----------------
// tid&31 = col, tid>>5 = row-slice (8 slices x 4 rows).
__global__ __launch_bounds__(256) void gemm2es_kernel(const float* __restrict__ h1,
        const float* __restrict__ W, const float* __restrict__ a2s, const float* __restrict__ a2d,
        __half* __restrict__ z2h, float* __restrict__ es2x, float* __restrict__ ed2x) {
    __shared__ float hbuf[32 * FIN];   // 16 KB
    int tid = threadIdx.x;
    int c = tid & 31, slice = tid >> 5;
    float w[128];
    #pragma unroll
    for (int kk = 0; kk < 128; ++kk) w[kk] = W[kk * F2 + c];
    float as = a2s[c], ad = a2d[c];
    int rowBase = blockIdx.x * 32;
    for (int idx = tid * 4; idx < 32 * FIN; idx += 1024) {
        int r = idx >> 7, k = idx & 127;
        int n = rowBase + r;
        float4 v = (n < NN) ? *(const float4*)&h1[(size_t)n * FIN + k] : make_float4(0, 0, 0, 0);
        *(float4*)&hbuf[idx] = v;
    }
    __syncthreads();
    int r0 = slice * 4;
    float acc[4] = {0.f, 0.f, 0.f, 0.f};
    #pragma unroll
    for (int k = 0; k < 128; k += 4) {
        #pragma unroll
        for (int rr = 0; rr < 4; ++rr) {
            float4 hv = *(float4*)&hbuf[(r0 + rr) * FIN + k];
            acc[rr] = fmaf(hv.x, w[k], fmaf(hv.y, w[k+1], fmaf(hv.z, w[k+2], fmaf(hv.w, w[k+3], acc[rr]))));
        }
    }
    #pragma unroll
    for (int rr = 0; rr < 4; ++rr) {
        int row = rowBase + r0 + rr;
        float z = acc[rr];
        float s = z * as, d = z * ad;
        #pragma unroll
        for (int o = 1; o < 32; o <<= 1) { s += __shfl_xor(s, o, 64); d += __shfl_xor(d, o, 64); }
        if (row < NN) {
            z2h[(size_t)row * F2 + c] = __float2half(z);
            if (c == 0) {
                es2x[row] = s * LOG2E;
                ed2x[row] = d * LOG2E;
            }
        }
    }
}

// ---------------- attention layer 1: single-pass, wave per dst node ----------------
// acc = sum w*z, ws = sum w; out = acc/ws. lane = 8*g + r; g = edge slot, r = head.
__global__ __launch_bounds__(256) void attn1_kernel(const int* __restrict__ row_ptr,
        const int* __restrict__ csr_src, const __half* __restrict__ z1h,
        const float* __restrict__ es, const float* __restrict__ ed,
        float* __restrict__ h1out) {
    int wid = (blockIdx.x * 256 + threadIdx.x) >> 6;
    int lane = threadIdx.x & 63;
    if (wid >= NN) return;
    int start = row_ptr[wid], end = row_ptr[wid + 1];
    int g = lane >> 3, r = lane & 7;
    float edn = ed[wid * NH + r];
    float acc[16];
    #pragma unroll
    for (int t = 0; t < 16; ++t) acc[t] = 0.f;
    float ws = 0.f;
    for (int i = start + g; i < end; i += 8) {
        int s = csr_src[i];
        float e = es[s * NH + r] + edn;
        float wv = exp2f(e >= 0.f ? e : SLOPE * e);
        ws += wv;
        const __half* zp = &z1h[(size_t)s * F1 + r * 16];
        union { float4 f; __half2 h2[4]; } u0, u1;
        u0.f = *(const float4*)zp;
        u1.f = *(const float4*)(zp + 8);
        #pragma unroll
        for (int j = 0; j < 4; ++j) {
            float2 v0 = __half22float2(u0.h2[j]);
            float2 v1 = __half22float2(u1.h2[j]);
            acc[2*j]     = fmaf(wv, v0.x, acc[2*j]);
            acc[2*j+1]   = fmaf(wv, v0.y, acc[2*j+1]);
            acc[8+2*j]   = fmaf(wv, v1.x, acc[8+2*j]);
            acc[8+2*j+1] = fmaf(wv, v1.y, acc[8+2*j+1]);
        }
    }
    ws += __shfl_xor(ws, 8, 64);
    ws += __shfl_xor(ws, 16, 64);
    ws += __shfl_xor(ws, 32, 64);
    #pragma unroll
    for (int t = 0; t < 16; ++t) {
        acc[t] += __shfl_xor(acc[t], 8, 64);
        acc[t] += __shfl_xor(acc[t], 16, 64);
        acc[t] += __shfl_xor(acc[t], 32, 64);
    }
    float rs = ws > 0.f ? 1.0f / ws : 0.f;
    if (g == 0) {
        float* op = &h1out[(size_t)wid * F1 + r * 16];
        #pragma unroll
        for (int t = 0; t < 16; t += 4) {
            float4 o;
            float v0 = acc[t] * rs, v1 = acc[t+1] * rs, v2 = acc[t+2] * rs, v3 = acc[t+3] * rs;
            o.x = v0 > 0.f ? v0 : expm1f(v0);
            o.y = v1 > 0.f ? v1 : expm1f(v1);
            o.z = v2 > 0.f ? v2 : expm1f(v2);
            o.w = v3 > 0.f ? v3 : expm1f(v3);
            *(float4*)&op[t] = o;
        }
    }
}

// ---------------- attention layer 2: single-pass, wave per dst node ----------------
// lane = 4*q + r; q = 16 edge slots, r = 4 col-groups of 8.
__global__ __launch_bounds__(256) void attn2_kernel(const int* __restrict__ row_ptr,
        const int* __restrict__ csr_src, const __half* __restrict__ z2h,
        const float* __restrict__ es, const float* __restrict__ ed,
        float* __restrict__ out) {
    int wid = (blockIdx.x * 256 + threadIdx.x) >> 6;
    int lane = threadIdx.x & 63;
    if (wid >= NN) return;
    int start = row_ptr[wid], end = row_ptr[wid + 1];
    int q = lane >> 2, r = lane & 3;
    float edn = ed[wid];
    float acc[8];
    #pragma unroll
    for (int t = 0; t < 8; ++t) acc[t] = 0.f;
    float ws = 0.f;
    for (int i = start + q; i < end; i += 16) {
        int s = csr_src[i];
        float e = es[s] + edn;
        float wv = exp2f(e >= 0.f ? e : SLOPE * e);
        ws += wv;
        union { float4 f; __half2 h2[4]; } u;
        u.f = *(const float4*)&z2h[(size_t)s * F2 + r * 8];
        #pragma unroll
        for (int j = 0; j < 4; ++j) {
            float2 v = __half22float2(u.h2[j]);
            acc[2*j]   = fmaf(wv, v.x, acc[2*j]);
            acc[2*j+1] = fmaf(wv, v.y, acc[2*j+1]);
        }
    }
    ws += __shfl_xor(ws, 4, 64);
    ws += __shfl_xor(ws, 8, 64);
    ws += __shfl_xor(ws, 16, 64);
    ws += __shfl_xor(ws, 32, 64);
    #pragma unroll
    for (int t = 0; t < 8; ++t) {
        acc[t] += __shfl_xor(acc[t], 4, 64);
        acc[t] += __shfl_xor(acc[t], 8, 64);
        acc[t] += __shfl_xor(acc[t], 16, 64);
        acc[t] += __shfl_xor(acc[t], 32, 64);
    }
    float rs = ws > 0.f ? 1.0f / ws : 0.f;
    if (q == 0) {
        float* op = &out[(size_t)wid * F2 + r * 8];
        *(float4*)&op[0] = make_float4(acc[0]*rs, acc[1]*rs, acc[2]*rs, acc[3]*rs);
        *(float4*)&op[4] = make_float4(acc[4]*rs, acc[5]*rs, acc[6]*rs, acc[7]*rs);
    }
}

extern "C" void kernel_launch(void* const* d_in, const int* in_sizes, int n_in,
                              void* d_out, int out_size, void* d_ws, size_t ws_size,
                              hipStream_t stream) {
    const float* h   = (const float*)d_in[0];
    const float* W1  = (const float*)d_in[1];
    const float* a1s = (const float*)d_in[2];
    const float* a1d = (const float*)d_in[3];
    const float* W2  = (const float*)d_in[4];
    const float* a2s = (const float*)d_in[5];
    const float* a2d = (const float*)d_in[6];
    const int*   src = (const int*)d_in[7];
    const int*   dst = (const int*)d_in[8];
    float* out = (float*)d_out;

    // workspace layout (4-byte elements); float regions kept 16B-aligned
    int* ip       = (int*)d_ws;
    int* deg      = ip;                      // NN
    int* fill     = deg + NN;                // NN (adjacent -> one memset)
    int* row_ptr  = fill + NN;               // NN+1
    int* partials = row_ptr + NN + 1;        // 256
    int* pscan    = partials + 256;          // 256
    int* csr_src  = pscan + 256;             // EE
    size_t off = (size_t)((csr_src + EE) - ip);
    off = (off + 3) & ~(size_t)3;            // 16B align
    float* es1x = (float*)(ip + off);        // NN*8
    float* ed1x = es1x + (size_t)NN * NH;    // NN*8
    float* h1   = ed1x + (size_t)NN * NH;    // NN*128
    float* es2x = h1 + (size_t)NN * F1;      // NN
    float* ed2x = es2x + NN;                 // NN
    float* fend = ed2x + NN;
    size_t fo = (size_t)(fend - (float*)(ip + off));
    fo = (fo + 3) & ~(size_t)3;
    __half* z1h = (__half*)((float*)(ip + off) + fo);  // NN*128 halfs
    __half* z2h = z1h + (size_t)NN * F1;               // NN*32 halfs

    hipMemsetAsync(deg, 0, (size_t)2 * NN * sizeof(int), stream);

    int eb = (EE + 255) / 256;
    int nb = (NN + 255) / 256;
    degree_kernel<<<eb, 256, 0, stream>>>(dst, deg);
    partial_sum_kernel<<<nb, 256, 0, stream>>>(deg, partials);
    scan_partials_kernel<<<1, 64, 0, stream>>>(partials, pscan, nb);
    scan_kernel<<<nb, 256, 0, stream>>>(deg, pscan, row_ptr);
    scatter_kernel<<<eb, 256, 0, stream>>>(src, dst, row_ptr, fill, csr_src);

    int gb = (NN + 31) / 32;
    gemm1es_kernel<<<gb, 256, 0, stream>>>(h, W1, a1s, a1d, z1h, es1x, ed1x);
    attn1_kernel<<<(NN * 64) / 256, 256, 0, stream>>>(row_ptr, csr_src, z1h, es1x, ed1x, h1);
    gemm2es_kernel<<<gb, 256, 0, stream>>>(h1, W2, a2s, a2d, z2h, es2x, ed2x);
    attn2_kernel<<<(NN * 64) / 256, 256, 0, stream>>>(row_ptr, csr_src, z2h, es2x, ed2x, out);
}

// Round 6
// 280.184 us; speedup vs baseline: 1.6332x; 1.6332x over previous
//
#include <hip/hip_runtime.h>
#include <hip/hip_fp16.h>
#include <math.h>

#define NN 50000
#define EE 800000
#define FIN 128
#define F1  128   // HEADS*HID
#define NH  8
#define DH  16
#define F2  32
#define SLOPE 0.2f
#define LOG2E 1.44269504f

typedef _Float16 f16x8 __attribute__((ext_vector_type(8)));
typedef float    f32x4 __attribute__((ext_vector_type(4)));

// ---------------- CSR build ----------------
__global__ void degree_kernel(const int* __restrict__ dst, int* __restrict__ deg) {
    int i = blockIdx.x * 256 + threadIdx.x;
    if (i < EE) atomicAdd(&deg[dst[i]], 1);
}

__global__ void partial_sum_kernel(const int* __restrict__ deg, int* __restrict__ partials) {
    __shared__ int sh[256];
    int i = blockIdx.x * 256 + threadIdx.x;
    sh[threadIdx.x] = (i < NN) ? deg[i] : 0;
    __syncthreads();
    for (int off = 128; off > 0; off >>= 1) {
        if (threadIdx.x < off) sh[threadIdx.x] += sh[threadIdx.x + off];
        __syncthreads();
    }
    if (threadIdx.x == 0) partials[blockIdx.x] = sh[0];
}

__global__ void scan_partials_kernel(const int* __restrict__ partials, int* __restrict__ pscan, int nblk) {
    int lane = threadIdx.x;   // 64 lanes, lane i owns indices [4i, 4i+4)
    int v[4], e[4];
    #pragma unroll
    for (int j = 0; j < 4; ++j) {
        int idx = lane * 4 + j;
        v[j] = (idx < nblk) ? partials[idx] : 0;
    }
    e[0] = 0; e[1] = v[0]; e[2] = v[0] + v[1]; e[3] = e[2] + v[2];
    int tot = e[3] + v[3];
    int inc = tot;
    #pragma unroll
    for (int off = 1; off < 64; off <<= 1) {
        int u = __shfl_up(inc, off, 64);
        if (lane >= off) inc += u;
    }
    int base = inc - tot;
    #pragma unroll
    for (int j = 0; j < 4; ++j) {
        int idx = lane * 4 + j;
        if (idx < nblk) pscan[idx] = base + e[j];
    }
}

__global__ void scan_kernel(const int* __restrict__ deg, const int* __restrict__ pscan,
                            int* __restrict__ row_ptr) {
    __shared__ int sh[256];
    int tid = threadIdx.x;
    int i = blockIdx.x * 256 + tid;
    int v = (i < NN) ? deg[i] : 0;
    sh[tid] = v;
    __syncthreads();
    for (int off = 1; off < 256; off <<= 1) {
        int t = (tid >= off) ? sh[tid - off] : 0;
        __syncthreads();
        sh[tid] += t;
        __syncthreads();
    }
    if (i < NN) row_ptr[i] = pscan[blockIdx.x] + sh[tid] - v;
    if (i == 0) row_ptr[NN] = EE;
}

__global__ void scatter_kernel(const int* __restrict__ src, const int* __restrict__ dst,
                               const int* __restrict__ row_ptr, int* __restrict__ fill,
                               int* __restrict__ csr_src) {
    int i = blockIdx.x * 256 + threadIdx.x;
    if (i < EE) {
        int d = dst[i];
        int pos = row_ptr[d] + atomicAdd(&fill[d], 1);
        csr_src[pos] = src[i];
    }
}

// ---------------- GEMM1 (MFMA fp16) + fp32 es/ed epilogue ----------------
// z1[N,128] = h[N,128] @ W1[128,128]. Block: 64 rows x 128 cols, 4 waves.
// es/ed computed from the fp32 MFMA accumulators (head t = fragment index t,
// 16 dims = 16 lanes of a quad -> intra-quad shfl reduction), THEN z stored fp16.
__global__ __launch_bounds__(256) void gemm1_kernel(const float* __restrict__ h,
        const float* __restrict__ W, const float* __restrict__ a1s, const float* __restrict__ a1d,
        __half* __restrict__ z1h, float* __restrict__ es1x, float* __restrict__ ed1x) {
    __shared__ alignas(16) __half hs[64 * 136];     // 17.4 KB
    __shared__ alignas(16) __half wls[128 * 136];   // 34.8 KB
    int tid = threadIdx.x;
    // stage W1^T fp16: wls[n*136 + k] = W[k*128 + n]
    for (int idx = tid; idx < FIN * F1; idx += 256) {
        int k = idx >> 7, n = idx & 127;
        wls[n * 136 + k] = __float2half(W[idx]);
    }
    // stage h tile fp32 -> fp16
    int rowBase = blockIdx.x * 64;
    for (int idx4 = tid; idx4 < 64 * 32; idx4 += 256) {
        int r = idx4 >> 5, cc = (idx4 & 31) * 4;
        int n = rowBase + r;
        float4 v = (n < NN) ? *(const float4*)&h[(size_t)n * FIN + cc] : make_float4(0, 0, 0, 0);
        union { __half2 h2[2]; int2 i; } u;
        u.h2[0] = __floats2half2_rn(v.x, v.y);
        u.h2[1] = __floats2half2_rn(v.z, v.w);
        *(int2*)&hs[r * 136 + cc] = u.i;
    }
    __syncthreads();
    int l = tid & 63, w = tid >> 6;
    int q = l >> 4, cl = l & 15;
    int m0 = w * 16;
    float as[8], ad[8];
    #pragma unroll
    for (int t = 0; t < 8; ++t) { as[t] = a1s[t * DH + cl]; ad[t] = a1d[t * DH + cl]; }
    f32x4 acc[8];
    #pragma unroll
    for (int t = 0; t < 8; ++t) acc[t] = (f32x4){0.f, 0.f, 0.f, 0.f};
    const __half* ap = &hs[(m0 + cl) * 136 + q * 8];
    const __half* bp = &wls[cl * 136 + q * 8];
    #pragma unroll
    for (int k0 = 0; k0 < 128; k0 += 32) {
        f16x8 af = *(const f16x8*)(ap + k0);
        #pragma unroll
        for (int t = 0; t < 8; ++t) {
            f16x8 bf = *(const f16x8*)(bp + t * 16 * 136 + k0);
            acc[t] = __builtin_amdgcn_mfma_f32_16x16x32_f16(af, bf, acc[t], 0, 0, 0);
        }
    }
    // C layout: col = t*16 + cl, row = rowBase + m0 + q*4 + reg
    #pragma unroll
    for (int t = 0; t < 8; ++t) {
        #pragma unroll
        for (int reg = 0; reg < 4; ++reg) {
            int row = rowBase + m0 + q * 4 + reg;
            float z = acc[t][reg];
            float s = z * as[t], d = z * ad[t];
            s += __shfl_xor(s, 1, 64); d += __shfl_xor(d, 1, 64);
            s += __shfl_xor(s, 2, 64); d += __shfl_xor(d, 2, 64);
            s += __shfl_xor(s, 4, 64); d += __shfl_xor(d, 4, 64);
            s += __shfl_xor(s, 8, 64); d += __shfl_xor(d, 8, 64);
            if (row < NN) {
                z1h[(size_t)row * F1 + t * 16 + cl] = __float2half(z);
                if (cl == 0) {
                    es1x[row * NH + t] = s * LOG2E;
                    ed1x[row * NH + t] = d * LOG2E;
                }
            }
        }
    }
}

// ---------------- GEMM2 (MFMA fp16) + fp32 es/ed epilogue ----------------
// z2[N,32] = h1h[N,128] @ W2[128,32]; single head over all 32 cols.
__global__ __launch_bounds__(256) void gemm2_kernel(const __half* __restrict__ h1h,
        const float* __restrict__ W, const float* __restrict__ a2s, const float* __restrict__ a2d,
        __half* __restrict__ z2h, float* __restrict__ es2x, float* __restrict__ ed2x) {
    __shared__ alignas(16) __half hs[64 * 136];    // 17.4 KB
    __shared__ alignas(16) __half wls[32 * 136];   // 8.7 KB
    int tid = threadIdx.x;
    for (int idx = tid; idx < FIN * F2; idx += 256) {
        int k = idx >> 5, n = idx & 31;
        wls[n * 136 + k] = __float2half(W[idx]);
    }
    int rowBase = blockIdx.x * 64;
    for (int idx8 = tid; idx8 < 64 * 16; idx8 += 256) {
        int r = idx8 >> 4, cc = (idx8 & 15) * 8;
        int n = rowBase + r;
        float4 v = make_float4(0, 0, 0, 0);
        if (n < NN) v = *(const float4*)&h1h[(size_t)n * FIN + cc];
        *(float4*)&hs[r * 136 + cc] = v;
    }
    __syncthreads();
    int l = tid & 63, w = tid >> 6;
    int q = l >> 4, cl = l & 15;
    int m0 = w * 16;
    float as0 = a2s[cl], as1 = a2s[16 + cl];
    float ad0 = a2d[cl], ad1 = a2d[16 + cl];
    f32x4 acc[2];
    acc[0] = (f32x4){0.f, 0.f, 0.f, 0.f};
    acc[1] = (f32x4){0.f, 0.f, 0.f, 0.f};
    const __half* ap = &hs[(m0 + cl) * 136 + q * 8];
    const __half* bp = &wls[cl * 136 + q * 8];
    #pragma unroll
    for (int k0 = 0; k0 < 128; k0 += 32) {
        f16x8 af = *(const f16x8*)(ap + k0);
        #pragma unroll
        for (int t = 0; t < 2; ++t) {
            f16x8 bf = *(const f16x8*)(bp + t * 16 * 136 + k0);
            acc[t] = __builtin_amdgcn_mfma_f32_16x16x32_f16(af, bf, acc[t], 0, 0, 0);
        }
    }
    #pragma unroll
    for (int reg = 0; reg < 4; ++reg) {
        int row = rowBase + m0 + q * 4 + reg;
        float s = acc[0][reg] * as0 + acc[1][reg] * as1;
        float d = acc[0][reg] * ad0 + acc[1][reg] * ad1;
        s += __shfl_xor(s, 1, 64); d += __shfl_xor(d, 1, 64);
        s += __shfl_xor(s, 2, 64); d += __shfl_xor(d, 2, 64);
        s += __shfl_xor(s, 4, 64); d += __shfl_xor(d, 4, 64);
        s += __shfl_xor(s, 8, 64); d += __shfl_xor(d, 8, 64);
        if (row < NN) {
            z2h[(size_t)row * F2 + cl]      = __float2half(acc[0][reg]);
            z2h[(size_t)row * F2 + 16 + cl] = __float2half(acc[1][reg]);
            if (cl == 0) {
                es2x[row] = s * LOG2E;
                ed2x[row] = d * LOG2E;
            }
        }
    }
}

// ---------------- attention layer 1: single-pass, wave per dst node, fp16 out ----------------
__global__ __launch_bounds__(256) void attn1_kernel(const int* __restrict__ row_ptr,
        const int* __restrict__ csr_src, const __half* __restrict__ z1h,
        const float* __restrict__ es, const float* __restrict__ ed,
        __half* __restrict__ h1h) {
    int wid = (blockIdx.x * 256 + threadIdx.x) >> 6;
    int lane = threadIdx.x & 63;
    if (wid >= NN) return;
    int start = row_ptr[wid], end = row_ptr[wid + 1];
    int g = lane >> 3, r = lane & 7;   // g = edge slot, r = head
    float edn = ed[wid * NH + r];
    float acc[16];
    #pragma unroll
    for (int t = 0; t < 16; ++t) acc[t] = 0.f;
    float ws = 0.f;
    for (int i = start + g; i < end; i += 8) {
        int s = csr_src[i];
        float e = es[s * NH + r] + edn;
        float wv = exp2f(e >= 0.f ? e : SLOPE * e);
        ws += wv;
        const __half* zp = &z1h[(size_t)s * F1 + r * 16];
        union { float4 f; __half2 h2[4]; } u0, u1;
        u0.f = *(const float4*)zp;
        u1.f = *(const float4*)(zp + 8);
        #pragma unroll
        for (int j = 0; j < 4; ++j) {
            float2 v0 = __half22float2(u0.h2[j]);
            float2 v1 = __half22float2(u1.h2[j]);
            acc[2*j]     = fmaf(wv, v0.x, acc[2*j]);
            acc[2*j+1]   = fmaf(wv, v0.y, acc[2*j+1]);
            acc[8+2*j]   = fmaf(wv, v1.x, acc[8+2*j]);
            acc[8+2*j+1] = fmaf(wv, v1.y, acc[8+2*j+1]);
        }
    }
    ws += __shfl_xor(ws, 8, 64);
    ws += __shfl_xor(ws, 16, 64);
    ws += __shfl_xor(ws, 32, 64);
    #pragma unroll
    for (int t = 0; t < 16; ++t) {
        acc[t] += __shfl_xor(acc[t], 8, 64);
        acc[t] += __shfl_xor(acc[t], 16, 64);
        acc[t] += __shfl_xor(acc[t], 32, 64);
    }
    float rs = ws > 0.f ? 1.0f / ws : 0.f;
    if (g == 0) {
        float v[16];
        #pragma unroll
        for (int t = 0; t < 16; ++t) {
            float x = acc[t] * rs;
            v[t] = x > 0.f ? x : expm1f(x);   // ELU
        }
        union { float4 f; __half2 h2[4]; } p0, p1;
        #pragma unroll
        for (int j = 0; j < 4; ++j) {
            p0.h2[j] = __floats2half2_rn(v[2*j], v[2*j+1]);
            p1.h2[j] = __floats2half2_rn(v[8+2*j], v[8+2*j+1]);
        }
        __half* op = &h1h[(size_t)wid * F1 + r * 16];
        *(float4*)op = p0.f;
        *(float4*)(op + 8) = p1.f;
    }
}

// ---------------- attention layer 2: single-pass, wave per dst node ----------------
__global__ __launch_bounds__(256) void attn2_kernel(const int* __restrict__ row_ptr,
        const int* __restrict__ csr_src, const __half* __restrict__ z2h,
        const float* __restrict__ es, const float* __restrict__ ed,
        float* __restrict__ out) {
    int wid = (blockIdx.x * 256 + threadIdx.x) >> 6;
    int lane = threadIdx.x & 63;
    if (wid >= NN) return;
    int start = row_ptr[wid], end = row_ptr[wid + 1];
    int q = lane >> 2, r = lane & 3;   // 16 edge slots x 4 col-groups of 8
    float edn = ed[wid];
    float acc[8];
    #pragma unroll
    for (int t = 0; t < 8; ++t) acc[t] = 0.f;
    float ws = 0.f;
    for (int i = start + q; i < end; i += 16) {
        int s = csr_src[i];
        float e = es[s] + edn;
        float wv = exp2f(e >= 0.f ? e : SLOPE * e);
        ws += wv;
        union { float4 f; __half2 h2[4]; } u;
        u.f = *(const float4*)&z2h[(size_t)s * F2 + r * 8];
        #pragma unroll
        for (int j = 0; j < 4; ++j) {
            float2 v = __half22float2(u.h2[j]);
            acc[2*j]   = fmaf(wv, v.x, acc[2*j]);
            acc[2*j+1] = fmaf(wv, v.y, acc[2*j+1]);
        }
    }
    ws += __shfl_xor(ws, 4, 64);
    ws += __shfl_xor(ws, 8, 64);
    ws += __shfl_xor(ws, 16, 64);
    ws += __shfl_xor(ws, 32, 64);
    #pragma unroll
    for (int t = 0; t < 8; ++t) {
        acc[t] += __shfl_xor(acc[t], 4, 64);
        acc[t] += __shfl_xor(acc[t], 8, 64);
        acc[t] += __shfl_xor(acc[t], 16, 64);
        acc[t] += __shfl_xor(acc[t], 32, 64);
    }
    float rs = ws > 0.f ? 1.0f / ws : 0.f;
    if (q == 0) {
        float* op = &out[(size_t)wid * F2 + r * 8];
        *(float4*)&op[0] = make_float4(acc[0]*rs, acc[1]*rs, acc[2]*rs, acc[3]*rs);
        *(float4*)&op[4] = make_float4(acc[4]*rs, acc[5]*rs, acc[6]*rs, acc[7]*rs);
    }
}

extern "C" void kernel_launch(void* const* d_in, const int* in_sizes, int n_in,
                              void* d_out, int out_size, void* d_ws, size_t ws_size,
                              hipStream_t stream) {
    const float* h   = (const float*)d_in[0];
    const float* W1  = (const float*)d_in[1];
    const float* a1s = (const float*)d_in[2];
    const float* a1d = (const float*)d_in[3];
    const float* W2  = (const float*)d_in[4];
    const float* a2s = (const float*)d_in[5];
    const float* a2d = (const float*)d_in[6];
    const int*   src = (const int*)d_in[7];
    const int*   dst = (const int*)d_in[8];
    float* out = (float*)d_out;

    // workspace layout (4-byte units); fp regions 16B-aligned
    int* ip       = (int*)d_ws;
    int* deg      = ip;                      // NN
    int* fill     = deg + NN;                // NN (adjacent -> one memset)
    int* row_ptr  = fill + NN;               // NN+1
    int* partials = row_ptr + NN + 1;        // 256
    int* pscan    = partials + 256;          // 256
    int* csr_src  = pscan + 256;             // EE
    size_t off = (size_t)((csr_src + EE) - ip);
    off = (off + 3) & ~(size_t)3;
    float* es1x = (float*)(ip + off);        // NN*8
    float* ed1x = es1x + (size_t)NN * NH;    // NN*8
    float* es2x = ed1x + (size_t)NN * NH;    // NN
    float* ed2x = es2x + NN;                 // NN
    float* fend = ed2x + NN;                 // multiple of 4 floats from 16B base
    __half* z1h = (__half*)fend;             // NN*128
    __half* h1h = z1h + (size_t)NN * F1;     // NN*128
    __half* z2h = h1h + (size_t)NN * F1;     // NN*32

    hipMemsetAsync(deg, 0, (size_t)2 * NN * sizeof(int), stream);

    int eb = (EE + 255) / 256;
    int nb = (NN + 255) / 256;
    degree_kernel<<<eb, 256, 0, stream>>>(dst, deg);
    partial_sum_kernel<<<nb, 256, 0, stream>>>(deg, partials);
    scan_partials_kernel<<<1, 64, 0, stream>>>(partials, pscan, nb);
    scan_kernel<<<nb, 256, 0, stream>>>(deg, pscan, row_ptr);
    scatter_kernel<<<eb, 256, 0, stream>>>(src, dst, row_ptr, fill, csr_src);

    int gb = (NN + 63) / 64;
    gemm1_kernel<<<gb, 256, 0, stream>>>(h, W1, a1s, a1d, z1h, es1x, ed1x);
    attn1_kernel<<<(NN * 64) / 256, 256, 0, stream>>>(row_ptr, csr_src, z1h, es1x, ed1x, h1h);
    gemm2_kernel<<<gb, 256, 0, stream>>>(h1h, W2, a2s, a2d, z2h, es2x, ed2x);
    attn2_kernel<<<(NN * 64) / 256, 256, 0, stream>>>(row_ptr, csr_src, z2h, es2x, ed2x, out);
}

// Round 7
// 245.133 us; speedup vs baseline: 1.8667x; 1.1430x over previous
//
#include <hip/hip_runtime.h>
#include <hip/hip_fp16.h>
#include <math.h>

#define NN 50000
#define EE 800000
#define FIN 128
#define F1  128   // HEADS*HID
#define NH  8
#define DH  16
#define F2  32
#define CAP 64    // bucket capacity; deg ~ Poisson(16), P(>64) ~ 1e-20
#define SLOPE 0.2f
#define LOG2E 1.44269504f

typedef _Float16 f16x8 __attribute__((ext_vector_type(8)));
typedef float    f32x4 __attribute__((ext_vector_type(4)));

// ---------------- bucket scatter: fill[d] counts, csr[d*64+pos] = src ----------------
__global__ __launch_bounds__(256) void scatter_kernel(const int* __restrict__ src,
        const int* __restrict__ dst, int* __restrict__ fill, int* __restrict__ csr) {
    int i4 = (blockIdx.x * 256 + threadIdx.x) * 4;
    if (i4 >= EE) return;                      // EE % 4 == 0, no partial tail
    int4 d4 = *(const int4*)&dst[i4];
    int4 s4 = *(const int4*)&src[i4];
    int p0 = atomicAdd(&fill[d4.x], 1);
    int p1 = atomicAdd(&fill[d4.y], 1);
    int p2 = atomicAdd(&fill[d4.z], 1);
    int p3 = atomicAdd(&fill[d4.w], 1);
    if (p0 < CAP) csr[d4.x * CAP + p0] = s4.x;
    if (p1 < CAP) csr[d4.y * CAP + p1] = s4.y;
    if (p2 < CAP) csr[d4.z * CAP + p2] = s4.z;
    if (p3 < CAP) csr[d4.w * CAP + p3] = s4.w;
}

// ---------------- GEMM1 (MFMA fp16) + fp32 es/ed epilogue ----------------
__global__ __launch_bounds__(256) void gemm1_kernel(const float* __restrict__ h,
        const float* __restrict__ W, const float* __restrict__ a1s, const float* __restrict__ a1d,
        __half* __restrict__ z1h, float* __restrict__ es1x, float* __restrict__ ed1x) {
    __shared__ alignas(16) __half hs[64 * 136];     // 17.4 KB
    __shared__ alignas(16) __half wls[128 * 136];   // 34.8 KB
    int tid = threadIdx.x;
    for (int idx = tid; idx < FIN * F1; idx += 256) {
        int k = idx >> 7, n = idx & 127;
        wls[n * 136 + k] = __float2half(W[idx]);
    }
    int rowBase = blockIdx.x * 64;
    for (int idx4 = tid; idx4 < 64 * 32; idx4 += 256) {
        int r = idx4 >> 5, cc = (idx4 & 31) * 4;
        int n = rowBase + r;
        float4 v = (n < NN) ? *(const float4*)&h[(size_t)n * FIN + cc] : make_float4(0, 0, 0, 0);
        union { __half2 h2[2]; int2 i; } u;
        u.h2[0] = __floats2half2_rn(v.x, v.y);
        u.h2[1] = __floats2half2_rn(v.z, v.w);
        *(int2*)&hs[r * 136 + cc] = u.i;
    }
    __syncthreads();
    int l = tid & 63, w = tid >> 6;
    int q = l >> 4, cl = l & 15;
    int m0 = w * 16;
    float as[8], ad[8];
    #pragma unroll
    for (int t = 0; t < 8; ++t) { as[t] = a1s[t * DH + cl]; ad[t] = a1d[t * DH + cl]; }
    f32x4 acc[8];
    #pragma unroll
    for (int t = 0; t < 8; ++t) acc[t] = (f32x4){0.f, 0.f, 0.f, 0.f};
    const __half* ap = &hs[(m0 + cl) * 136 + q * 8];
    const __half* bp = &wls[cl * 136 + q * 8];
    #pragma unroll
    for (int k0 = 0; k0 < 128; k0 += 32) {
        f16x8 af = *(const f16x8*)(ap + k0);
        #pragma unroll
        for (int t = 0; t < 8; ++t) {
            f16x8 bf = *(const f16x8*)(bp + t * 16 * 136 + k0);
            acc[t] = __builtin_amdgcn_mfma_f32_16x16x32_f16(af, bf, acc[t], 0, 0, 0);
        }
    }
    #pragma unroll
    for (int t = 0; t < 8; ++t) {
        #pragma unroll
        for (int reg = 0; reg < 4; ++reg) {
            int row = rowBase + m0 + q * 4 + reg;
            float z = acc[t][reg];
            float s = z * as[t], d = z * ad[t];
            s += __shfl_xor(s, 1, 64); d += __shfl_xor(d, 1, 64);
            s += __shfl_xor(s, 2, 64); d += __shfl_xor(d, 2, 64);
            s += __shfl_xor(s, 4, 64); d += __shfl_xor(d, 4, 64);
            s += __shfl_xor(s, 8, 64); d += __shfl_xor(d, 8, 64);
            if (row < NN) {
                z1h[(size_t)row * F1 + t * 16 + cl] = __float2half(z);
                if (cl == 0) {
                    es1x[row * NH + t] = s * LOG2E;
                    ed1x[row * NH + t] = d * LOG2E;
                }
            }
        }
    }
}

// ---------------- GEMM2 (MFMA fp16) + fp32 es/ed epilogue ----------------
__global__ __launch_bounds__(256) void gemm2_kernel(const __half* __restrict__ h1h,
        const float* __restrict__ W, const float* __restrict__ a2s, const float* __restrict__ a2d,
        __half* __restrict__ z2h, float* __restrict__ es2x, float* __restrict__ ed2x) {
    __shared__ alignas(16) __half hs[64 * 136];    // 17.4 KB
    __shared__ alignas(16) __half wls[32 * 136];   // 8.7 KB
    int tid = threadIdx.x;
    for (int idx = tid; idx < FIN * F2; idx += 256) {
        int k = idx >> 5, n = idx & 31;
        wls[n * 136 + k] = __float2half(W[idx]);
    }
    int rowBase = blockIdx.x * 64;
    for (int idx8 = tid; idx8 < 64 * 16; idx8 += 256) {
        int r = idx8 >> 4, cc = (idx8 & 15) * 8;
        int n = rowBase + r;
        float4 v = make_float4(0, 0, 0, 0);
        if (n < NN) v = *(const float4*)&h1h[(size_t)n * FIN + cc];
        *(float4*)&hs[r * 136 + cc] = v;
    }
    __syncthreads();
    int l = tid & 63, w = tid >> 6;
    int q = l >> 4, cl = l & 15;
    int m0 = w * 16;
    float as0 = a2s[cl], as1 = a2s[16 + cl];
    float ad0 = a2d[cl], ad1 = a2d[16 + cl];
    f32x4 acc[2];
    acc[0] = (f32x4){0.f, 0.f, 0.f, 0.f};
    acc[1] = (f32x4){0.f, 0.f, 0.f, 0.f};
    const __half* ap = &hs[(m0 + cl) * 136 + q * 8];
    const __half* bp = &wls[cl * 136 + q * 8];
    #pragma unroll
    for (int k0 = 0; k0 < 128; k0 += 32) {
        f16x8 af = *(const f16x8*)(ap + k0);
        #pragma unroll
        for (int t = 0; t < 2; ++t) {
            f16x8 bf = *(const f16x8*)(bp + t * 16 * 136 + k0);
            acc[t] = __builtin_amdgcn_mfma_f32_16x16x32_f16(af, bf, acc[t], 0, 0, 0);
        }
    }
    #pragma unroll
    for (int reg = 0; reg < 4; ++reg) {
        int row = rowBase + m0 + q * 4 + reg;
        float s = acc[0][reg] * as0 + acc[1][reg] * as1;
        float d = acc[0][reg] * ad0 + acc[1][reg] * ad1;
        s += __shfl_xor(s, 1, 64); d += __shfl_xor(d, 1, 64);
        s += __shfl_xor(s, 2, 64); d += __shfl_xor(d, 2, 64);
        s += __shfl_xor(s, 4, 64); d += __shfl_xor(d, 4, 64);
        s += __shfl_xor(s, 8, 64); d += __shfl_xor(d, 8, 64);
        if (row < NN) {
            z2h[(size_t)row * F2 + cl]      = __float2half(acc[0][reg]);
            z2h[(size_t)row * F2 + 16 + cl] = __float2half(acc[1][reg]);
            if (cl == 0) {
                es2x[row] = s * LOG2E;
                ed2x[row] = d * LOG2E;
            }
        }
    }
}

// ---------------- attention layer 1: 16 lanes per node, reduction-free ----------------
// lane j of node n owns dims [8j, 8j+8) (head j>>1). Each lane accumulates its own
// acc[8] and ws across the node's bucket — no shuffles, no cross-lane epilogue.
__global__ __launch_bounds__(256) void attn1_kernel(const int* __restrict__ fill,
        const int* __restrict__ csr, const __half* __restrict__ z1h,
        const float* __restrict__ es, const float* __restrict__ ed,
        __half* __restrict__ h1h) {
    int gt = blockIdx.x * 256 + threadIdx.x;
    int n = gt >> 4;          // node
    int j = gt & 15;          // dim-group lane
    int hl = j >> 1;          // head
    if (n >= NN) return;
    int cnt = fill[n];
    if (cnt > CAP) cnt = CAP;
    int base = n * CAP;
    float edn = ed[n * NH + hl];
    float acc[8] = {0.f, 0.f, 0.f, 0.f, 0.f, 0.f, 0.f, 0.f};
    float ws = 0.f;
    for (int i = 0; i < cnt; ++i) {
        int s = csr[base + i];
        float e = es[s * NH + hl] + edn;
        e = e >= 0.f ? e : SLOPE * e;
        float wv = exp2f(e);
        ws += wv;
        union { float4 f; __half2 h2[4]; } u;
        u.f = *(const float4*)&z1h[(size_t)s * F1 + j * 8];
        #pragma unroll
        for (int t = 0; t < 4; ++t) {
            float2 v = __half22float2(u.h2[t]);
            acc[2*t]   = fmaf(wv, v.x, acc[2*t]);
            acc[2*t+1] = fmaf(wv, v.y, acc[2*t+1]);
        }
    }
    float rs = ws > 0.f ? 1.0f / ws : 0.f;
    union { float4 f; __half2 h2[4]; } p;
    #pragma unroll
    for (int t = 0; t < 4; ++t) {
        float x0 = acc[2*t] * rs, x1 = acc[2*t+1] * rs;
        x0 = x0 > 0.f ? x0 : __expf(x0) - 1.0f;   // ELU (abs err ~1e-7, fine)
        x1 = x1 > 0.f ? x1 : __expf(x1) - 1.0f;
        p.h2[t] = __floats2half2_rn(x0, x1);
    }
    *(float4*)&h1h[(size_t)n * F1 + j * 8] = p.f;
}

// ---------------- attention layer 2: 4 lanes per node, reduction-free ----------------
__global__ __launch_bounds__(256) void attn2_kernel(const int* __restrict__ fill,
        const int* __restrict__ csr, const __half* __restrict__ z2h,
        const float* __restrict__ es, const float* __restrict__ ed,
        float* __restrict__ out) {
    int gt = blockIdx.x * 256 + threadIdx.x;
    int n = gt >> 2;          // node
    int j = gt & 3;           // dim-group lane: dims [8j, 8j+8)
    if (n >= NN) return;
    int cnt = fill[n];
    if (cnt > CAP) cnt = CAP;
    int base = n * CAP;
    float edn = ed[n];
    float acc[8] = {0.f, 0.f, 0.f, 0.f, 0.f, 0.f, 0.f, 0.f};
    float ws = 0.f;
    for (int i = 0; i < cnt; ++i) {
        int s = csr[base + i];
        float e = es[s] + edn;
        e = e >= 0.f ? e : SLOPE * e;
        float wv = exp2f(e);
        ws += wv;
        union { float4 f; __half2 h2[4]; } u;
        u.f = *(const float4*)&z2h[(size_t)s * F2 + j * 8];
        #pragma unroll
        for (int t = 0; t < 4; ++t) {
            float2 v = __half22float2(u.h2[t]);
            acc[2*t]   = fmaf(wv, v.x, acc[2*t]);
            acc[2*t+1] = fmaf(wv, v.y, acc[2*t+1]);
        }
    }
    float rs = ws > 0.f ? 1.0f / ws : 0.f;
    float* op = &out[(size_t)n * F2 + j * 8];
    *(float4*)&op[0] = make_float4(acc[0]*rs, acc[1]*rs, acc[2]*rs, acc[3]*rs);
    *(float4*)&op[4] = make_float4(acc[4]*rs, acc[5]*rs, acc[6]*rs, acc[7]*rs);
}

extern "C" void kernel_launch(void* const* d_in, const int* in_sizes, int n_in,
                              void* d_out, int out_size, void* d_ws, size_t ws_size,
                              hipStream_t stream) {
    const float* h   = (const float*)d_in[0];
    const float* W1  = (const float*)d_in[1];
    const float* a1s = (const float*)d_in[2];
    const float* a1d = (const float*)d_in[3];
    const float* W2  = (const float*)d_in[4];
    const float* a2s = (const float*)d_in[5];
    const float* a2d = (const float*)d_in[6];
    const int*   src = (const int*)d_in[7];
    const int*   dst = (const int*)d_in[8];
    float* out = (float*)d_out;

    // workspace layout (all offsets 16B-aligned)
    int* ip     = (int*)d_ws;
    int* fill   = ip;                        // NN
    int* csr    = fill + NN;                 // NN*CAP  (12.8 MB)
    float* es1x = (float*)(csr + (size_t)NN * CAP);  // NN*8
    float* ed1x = es1x + (size_t)NN * NH;    // NN*8
    float* es2x = ed1x + (size_t)NN * NH;    // NN
    float* ed2x = es2x + NN;                 // NN
    __half* z1h = (__half*)(ed2x + NN);      // NN*128
    __half* h1h = z1h + (size_t)NN * F1;     // NN*128
    __half* z2h = h1h + (size_t)NN * F1;     // NN*32

    hipMemsetAsync(fill, 0, (size_t)NN * sizeof(int), stream);

    scatter_kernel<<<(EE / 4 + 255) / 256, 256, 0, stream>>>(src, dst, fill, csr);

    int gb = (NN + 63) / 64;
    gemm1_kernel<<<gb, 256, 0, stream>>>(h, W1, a1s, a1d, z1h, es1x, ed1x);
    attn1_kernel<<<(NN * 16 + 255) / 256, 256, 0, stream>>>(fill, csr, z1h, es1x, ed1x, h1h);
    gemm2_kernel<<<gb, 256, 0, stream>>>(h1h, W2, a2s, a2d, z2h, es2x, ed2x);
    attn2_kernel<<<(NN * 4 + 255) / 256, 256, 0, stream>>>(fill, csr, z2h, es2x, ed2x, out);
}

// Round 9
// 217.497 us; speedup vs baseline: 2.1039x; 1.1271x over previous
//
#include <hip/hip_runtime.h>
#include <hip/hip_fp16.h>
#include <math.h>

#define NN 50000
#define EE 800000
#define FIN 128
#define F1  128   // HEADS*HID
#define NH  8
#define DH  16
#define F2  32
#define SLOPE 0.2f
#define LOG2E 1.44269504f

#define EB 4096                    // edges per block in S1/S3
#define NBLK ((EE + EB - 1) / EB)  // 196
#define BK  391                    // coarse buckets = ceil(NN/128)
#define SEGCAP 4096                // max edges per bucket segment (mean 2046)

typedef _Float16 f16x8 __attribute__((ext_vector_type(8)));
typedef float    f32x4 __attribute__((ext_vector_type(4)));

// ---------------- S1: coarse histogram ----------------
__global__ __launch_bounds__(256) void hist_kernel(const int* __restrict__ dst,
        int* __restrict__ hist) {
    __shared__ int lc[BK];
    int tid = threadIdx.x;
    for (int i = tid; i < BK; i += 256) lc[i] = 0;
    __syncthreads();
    int base = blockIdx.x * EB;
    int end = base + EB; if (end > EE) end = EE;
    for (int i = base + tid; i < end; i += 256)
        atomicAdd(&lc[dst[i] >> 7], 1);
    __syncthreads();
    for (int i = tid; i < BK; i += 256)
        if (lc[i]) atomicAdd(&hist[i], lc[i]);
}

// ---------------- S2: scan histogram -> segment bases + cursors ----------------
__global__ __launch_bounds__(256) void scan_hist_kernel(const int* __restrict__ hist,
        int* __restrict__ basea, int* __restrict__ cursor) {
    __shared__ int sh[256];
    int tid = threadIdx.x;
    int a0 = hist[2 * tid], a1 = hist[2 * tid + 1];   // hist zero-padded to 512
    int tsum = a0 + a1;
    sh[tid] = tsum;
    __syncthreads();
    for (int off = 1; off < 256; off <<= 1) {
        int t = (tid >= off) ? sh[tid - off] : 0;
        __syncthreads();
        sh[tid] += t;
        __syncthreads();
    }
    int ex = sh[tid] - tsum;
    basea[2 * tid] = ex;     cursor[2 * tid] = ex;
    basea[2 * tid + 1] = ex + a0; cursor[2 * tid + 1] = ex + a0;
}

// ---------------- S3: multisplit into bucket-sorted packed records ----------------
// record = (dst << 16) | src, UNSIGNED (dst up to 49999 would overflow signed).
__global__ __launch_bounds__(256) void split_kernel(const int* __restrict__ src,
        const int* __restrict__ dst, int* __restrict__ cursor, unsigned int* __restrict__ sorted) {
    __shared__ int lc[512];             // padded counts
    __shared__ int lofs[512];           // exclusive scan
    __shared__ int lcur[BK];            // placement cursors
    __shared__ int delta[BK];           // global_base - local_base
    __shared__ int sh[256];
    __shared__ unsigned int recs[EB];   // 16 KB
    __shared__ unsigned short rbk[EB];  // 8 KB bucket id per slot
    int tid = threadIdx.x;
    for (int i = tid; i < 512; i += 256) lc[i] = 0;
    __syncthreads();
    int base = blockIdx.x * EB;
    int cnt = EE - base; if (cnt > EB) cnt = EB;
    unsigned int myrec[16];
    #pragma unroll
    for (int k = 0; k < 16; ++k) {
        int i = base + tid + k * 256;
        myrec[k] = 0xFFFFFFFFu;         // sentinel: dst=0xFFFF impossible (< 50000)
        if (i - base < cnt) {
            unsigned int d = (unsigned int)dst[i];
            myrec[k] = (d << 16) | (unsigned int)src[i];
            atomicAdd(&lc[d >> 7], 1);
        }
    }
    __syncthreads();
    // exclusive scan of lc[512]
    int a0 = lc[2 * tid], a1 = lc[2 * tid + 1];
    int tsum = a0 + a1;
    sh[tid] = tsum;
    __syncthreads();
    for (int off = 1; off < 256; off <<= 1) {
        int t = (tid >= off) ? sh[tid - off] : 0;
        __syncthreads();
        sh[tid] += t;
        __syncthreads();
    }
    int ex = sh[tid] - tsum;
    lofs[2 * tid] = ex;
    lofs[2 * tid + 1] = ex + a0;
    __syncthreads();
    // claim global ranges per bucket
    for (int b = tid; b < BK; b += 256) {
        int c = lc[b];
        lcur[b] = lofs[b];
        if (c) {
            int g = atomicAdd(&cursor[b], c);
            delta[b] = g - lofs[b];
        }
    }
    __syncthreads();
    // place records into LDS ordered by bucket
    #pragma unroll
    for (int k = 0; k < 16; ++k) {
        if (myrec[k] != 0xFFFFFFFFu) {
            int b = (int)(myrec[k] >> 23);      // dst >> 7
            int pos = atomicAdd(&lcur[b], 1);
            recs[pos] = myrec[k];
            rbk[pos] = (unsigned short)b;
        }
    }
    __syncthreads();
    // coalesced copy-out (consecutive slots -> mostly consecutive global addrs)
    for (int s = tid; s < cnt; s += 256)
        sorted[s + delta[rbk[s]]] = recs[s];
}

// ---------------- S4: per-bucket dense CSR build ----------------
__global__ __launch_bounds__(256) void csrbuild_kernel(const int* __restrict__ basea,
        const unsigned int* __restrict__ sorted, unsigned short* __restrict__ csr,
        int* __restrict__ row_ptr) {
    __shared__ unsigned int recs[SEGCAP];     // 16 KB
    __shared__ unsigned short csr_sh[SEGCAP]; // 8 KB
    __shared__ int ncnt[128], nofs[128], ncur[128];
    __shared__ int sh[256];
    int b = blockIdx.x;
    int tid = threadIdx.x;
    int s0 = basea[b], s1 = basea[b + 1];
    int cnt = s1 - s0; if (cnt > SEGCAP) cnt = SEGCAP;
    if (tid < 128) ncnt[tid] = 0;
    __syncthreads();
    for (int i = tid; i < cnt; i += 256) {
        unsigned int r = sorted[s0 + i];
        recs[i] = r;
        atomicAdd(&ncnt[(r >> 16) & 127], 1);
    }
    __syncthreads();
    int v = (tid < 128) ? ncnt[tid] : 0;
    sh[tid] = v;
    __syncthreads();
    for (int off = 1; off < 256; off <<= 1) {
        int t = (tid >= off) ? sh[tid - off] : 0;
        __syncthreads();
        sh[tid] += t;
        __syncthreads();
    }
    int ex = sh[tid] - v;
    if (tid < 128) {
        nofs[tid] = ex;
        ncur[tid] = ex;
        int node = b * 128 + tid;
        if (node < NN) row_ptr[node] = s0 + ex;
    }
    if (b == BK - 1 && tid == 0) row_ptr[NN] = EE;
    __syncthreads();
    for (int i = tid; i < cnt; i += 256) {
        unsigned int r = recs[i];
        int local = (r >> 16) & 127;
        int p = atomicAdd(&ncur[local], 1);
        csr_sh[p] = (unsigned short)(r & 0xFFFFu);
    }
    __syncthreads();
    for (int i = tid; i < cnt; i += 256)
        csr[s0 + i] = csr_sh[i];
}

// ---------------- GEMM1 (MFMA fp16) + fp32 es/ed epilogue ----------------
__global__ __launch_bounds__(256) void gemm1_kernel(const float* __restrict__ h,
        const float* __restrict__ W, const float* __restrict__ a1s, const float* __restrict__ a1d,
        __half* __restrict__ z1h, float* __restrict__ es1x, float* __restrict__ ed1x) {
    __shared__ alignas(16) __half hs[64 * 136];     // 17.4 KB
    __shared__ alignas(16) __half wls[128 * 136];   // 34.8 KB
    int tid = threadIdx.x;
    for (int idx = tid; idx < FIN * F1; idx += 256) {
        int k = idx >> 7, n = idx & 127;
        wls[n * 136 + k] = __float2half(W[idx]);
    }
    int rowBase = blockIdx.x * 64;
    for (int idx4 = tid; idx4 < 64 * 32; idx4 += 256) {
        int r = idx4 >> 5, cc = (idx4 & 31) * 4;
        int n = rowBase + r;
        float4 v = (n < NN) ? *(const float4*)&h[(size_t)n * FIN + cc] : make_float4(0, 0, 0, 0);
        union { __half2 h2[2]; int2 i; } u;
        u.h2[0] = __floats2half2_rn(v.x, v.y);
        u.h2[1] = __floats2half2_rn(v.z, v.w);
        *(int2*)&hs[r * 136 + cc] = u.i;
    }
    __syncthreads();
    int l = tid & 63, w = tid >> 6;
    int q = l >> 4, cl = l & 15;
    int m0 = w * 16;
    float as[8], ad[8];
    #pragma unroll
    for (int t = 0; t < 8; ++t) { as[t] = a1s[t * DH + cl]; ad[t] = a1d[t * DH + cl]; }
    f32x4 acc[8];
    #pragma unroll
    for (int t = 0; t < 8; ++t) acc[t] = (f32x4){0.f, 0.f, 0.f, 0.f};
    const __half* ap = &hs[(m0 + cl) * 136 + q * 8];
    const __half* bp = &wls[cl * 136 + q * 8];
    #pragma unroll
    for (int k0 = 0; k0 < 128; k0 += 32) {
        f16x8 af = *(const f16x8*)(ap + k0);
        #pragma unroll
        for (int t = 0; t < 8; ++t) {
            f16x8 bf = *(const f16x8*)(bp + t * 16 * 136 + k0);
            acc[t] = __builtin_amdgcn_mfma_f32_16x16x32_f16(af, bf, acc[t], 0, 0, 0);
        }
    }
    #pragma unroll
    for (int t = 0; t < 8; ++t) {
        #pragma unroll
        for (int reg = 0; reg < 4; ++reg) {
            int row = rowBase + m0 + q * 4 + reg;
            float z = acc[t][reg];
            float s = z * as[t], d = z * ad[t];
            s += __shfl_xor(s, 1, 64); d += __shfl_xor(d, 1, 64);
            s += __shfl_xor(s, 2, 64); d += __shfl_xor(d, 2, 64);
            s += __shfl_xor(s, 4, 64); d += __shfl_xor(d, 4, 64);
            s += __shfl_xor(s, 8, 64); d += __shfl_xor(d, 8, 64);
            if (row < NN) {
                z1h[(size_t)row * F1 + t * 16 + cl] = __float2half(z);
                if (cl == 0) {
                    es1x[row * NH + t] = s * LOG2E;
                    ed1x[row * NH + t] = d * LOG2E;
                }
            }
        }
    }
}

// ---------------- GEMM2 (MFMA fp16) + fp32 es/ed epilogue ----------------
__global__ __launch_bounds__(256) void gemm2_kernel(const __half* __restrict__ h1h,
        const float* __restrict__ W, const float* __restrict__ a2s, const float* __restrict__ a2d,
        __half* __restrict__ z2h, float* __restrict__ es2x, float* __restrict__ ed2x) {
    __shared__ alignas(16) __half hs[64 * 136];    // 17.4 KB
    __shared__ alignas(16) __half wls[32 * 136];   // 8.7 KB
    int tid = threadIdx.x;
    for (int idx = tid; idx < FIN * F2; idx += 256) {
        int k = idx >> 5, n = idx & 31;
        wls[n * 136 + k] = __float2half(W[idx]);
    }
    int rowBase = blockIdx.x * 64;
    for (int idx8 = tid; idx8 < 64 * 16; idx8 += 256) {
        int r = idx8 >> 4, cc = (idx8 & 15) * 8;
        int n = rowBase + r;
        float4 v = make_float4(0, 0, 0, 0);
        if (n < NN) v = *(const float4*)&h1h[(size_t)n * FIN + cc];
        *(float4*)&hs[r * 136 + cc] = v;
    }
    __syncthreads();
    int l = tid & 63, w = tid >> 6;
    int q = l >> 4, cl = l & 15;
    int m0 = w * 16;
    float as0 = a2s[cl], as1 = a2s[16 + cl];
    float ad0 = a2d[cl], ad1 = a2d[16 + cl];
    f32x4 acc[2];
    acc[0] = (f32x4){0.f, 0.f, 0.f, 0.f};
    acc[1] = (f32x4){0.f, 0.f, 0.f, 0.f};
    const __half* ap = &hs[(m0 + cl) * 136 + q * 8];
    const __half* bp = &wls[cl * 136 + q * 8];
    #pragma unroll
    for (int k0 = 0; k0 < 128; k0 += 32) {
        f16x8 af = *(const f16x8*)(ap + k0);
        #pragma unroll
        for (int t = 0; t < 2; ++t) {
            f16x8 bf = *(const f16x8*)(bp + t * 16 * 136 + k0);
            acc[t] = __builtin_amdgcn_mfma_f32_16x16x32_f16(af, bf, acc[t], 0, 0, 0);
        }
    }
    #pragma unroll
    for (int reg = 0; reg < 4; ++reg) {
        int row = rowBase + m0 + q * 4 + reg;
        float s = acc[0][reg] * as0 + acc[1][reg] * as1;
        float d = acc[0][reg] * ad0 + acc[1][reg] * ad1;
        s += __shfl_xor(s, 1, 64); d += __shfl_xor(d, 1, 64);
        s += __shfl_xor(s, 2, 64); d += __shfl_xor(d, 2, 64);
        s += __shfl_xor(s, 4, 64); d += __shfl_xor(d, 4, 64);
        s += __shfl_xor(s, 8, 64); d += __shfl_xor(d, 8, 64);
        if (row < NN) {
            z2h[(size_t)row * F2 + cl]      = __float2half(acc[0][reg]);
            z2h[(size_t)row * F2 + 16 + cl] = __float2half(acc[1][reg]);
            if (cl == 0) {
                es2x[row] = s * LOG2E;
                ed2x[row] = d * LOG2E;
            }
        }
    }
}

// ---------------- attention layer 1: 16 lanes per node, reduction-free ----------------
__global__ __launch_bounds__(256) void attn1_kernel(const int* __restrict__ row_ptr,
        const unsigned short* __restrict__ csr, const __half* __restrict__ z1h,
        const float* __restrict__ es, const float* __restrict__ ed,
        __half* __restrict__ h1h) {
    int gt = blockIdx.x * 256 + threadIdx.x;
    int n = gt >> 4;          // node
    int j = gt & 15;          // dim-group lane
    int hl = j >> 1;          // head
    if (n >= NN) return;
    int b0 = row_ptr[n];
    int cnt = row_ptr[n + 1] - b0;
    float edn = ed[n * NH + hl];
    float acc[8] = {0.f, 0.f, 0.f, 0.f, 0.f, 0.f, 0.f, 0.f};
    float ws = 0.f;
    for (int i = 0; i < cnt; ++i) {
        int s = csr[b0 + i];
        float e = es[s * NH + hl] + edn;
        e = e >= 0.f ? e : SLOPE * e;
        float wv = exp2f(e);
        ws += wv;
        union { float4 f; __half2 h2[4]; } u;
        u.f = *(const float4*)&z1h[(size_t)s * F1 + j * 8];
        #pragma unroll
        for (int t = 0; t < 4; ++t) {
            float2 v = __half22float2(u.h2[t]);
            acc[2*t]   = fmaf(wv, v.x, acc[2*t]);
            acc[2*t+1] = fmaf(wv, v.y, acc[2*t+1]);
        }
    }
    float rs = ws > 0.f ? 1.0f / ws : 0.f;
    union { float4 f; __half2 h2[4]; } p;
    #pragma unroll
    for (int t = 0; t < 4; ++t) {
        float x0 = acc[2*t] * rs, x1 = acc[2*t+1] * rs;
        x0 = x0 > 0.f ? x0 : __expf(x0) - 1.0f;   // ELU
        x1 = x1 > 0.f ? x1 : __expf(x1) - 1.0f;
        p.h2[t] = __floats2half2_rn(x0, x1);
    }
    *(float4*)&h1h[(size_t)n * F1 + j * 8] = p.f;
}

// ---------------- attention layer 2: 4 lanes per node, reduction-free ----------------
__global__ __launch_bounds__(256) void attn2_kernel(const int* __restrict__ row_ptr,
        const unsigned short* __restrict__ csr, const __half* __restrict__ z2h,
        const float* __restrict__ es, const float* __restrict__ ed,
        float* __restrict__ out) {
    int gt = blockIdx.x * 256 + threadIdx.x;
    int n = gt >> 2;          // node
    int j = gt & 3;           // dims [8j, 8j+8)
    if (n >= NN) return;
    int b0 = row_ptr[n];
    int cnt = row_ptr[n + 1] - b0;
    float edn = ed[n];
    float acc[8] = {0.f, 0.f, 0.f, 0.f, 0.f, 0.f, 0.f, 0.f};
    float ws = 0.f;
    for (int i = 0; i < cnt; ++i) {
        int s = csr[b0 + i];
        float e = es[s] + edn;
        e = e >= 0.f ? e : SLOPE * e;
        float wv = exp2f(e);
        ws += wv;
        union { float4 f; __half2 h2[4]; } u;
        u.f = *(const float4*)&z2h[(size_t)s * F2 + j * 8];
        #pragma unroll
        for (int t = 0; t < 4; ++t) {
            float2 v = __half22float2(u.h2[t]);
            acc[2*t]   = fmaf(wv, v.x, acc[2*t]);
            acc[2*t+1] = fmaf(wv, v.y, acc[2*t+1]);
        }
    }
    float rs = ws > 0.f ? 1.0f / ws : 0.f;
    float* op = &out[(size_t)n * F2 + j * 8];
    *(float4*)&op[0] = make_float4(acc[0]*rs, acc[1]*rs, acc[2]*rs, acc[3]*rs);
    *(float4*)&op[4] = make_float4(acc[4]*rs, acc[5]*rs, acc[6]*rs, acc[7]*rs);
}

extern "C" void kernel_launch(void* const* d_in, const int* in_sizes, int n_in,
                              void* d_out, int out_size, void* d_ws, size_t ws_size,
                              hipStream_t stream) {
    const float* h   = (const float*)d_in[0];
    const float* W1  = (const float*)d_in[1];
    const float* a1s = (const float*)d_in[2];
    const float* a1d = (const float*)d_in[3];
    const float* W2  = (const float*)d_in[4];
    const float* a2s = (const float*)d_in[5];
    const float* a2d = (const float*)d_in[6];
    const int*   src = (const int*)d_in[7];
    const int*   dst = (const int*)d_in[8];
    float* out = (float*)d_out;

    // workspace layout (4-byte units, fp regions 16B-aligned)
    int* ip      = (int*)d_ws;
    int* hist    = ip;                       // 512 (zeroed; only [0,BK) used)
    int* basea   = hist + 512;               // 520
    int* cursor  = basea + 520;              // 512
    int* row_ptr = cursor + 512;             // NN+1 -> pad to NN+8
    unsigned int* sorted = (unsigned int*)(row_ptr + NN + 8);  // EE
    unsigned short* csr16 = (unsigned short*)(sorted + EE);    // EE ushorts
    float* es1x = (float*)(csr16 + EE);      // NN*8
    float* ed1x = es1x + (size_t)NN * NH;    // NN*8
    float* es2x = ed1x + (size_t)NN * NH;    // NN
    float* ed2x = es2x + NN;                 // NN
    __half* z1h = (__half*)(ed2x + NN);      // NN*128
    __half* h1h = z1h + (size_t)NN * F1;     // NN*128
    __half* z2h = h1h + (size_t)NN * F1;     // NN*32

    hipMemsetAsync(hist, 0, 512 * sizeof(int), stream);

    hist_kernel<<<NBLK, 256, 0, stream>>>(dst, hist);
    scan_hist_kernel<<<1, 256, 0, stream>>>(hist, basea, cursor);
    split_kernel<<<NBLK, 256, 0, stream>>>(src, dst, cursor, sorted);
    csrbuild_kernel<<<BK, 256, 0, stream>>>(basea, sorted, csr16, row_ptr);

    int gb = (NN + 63) / 64;
    gemm1_kernel<<<gb, 256, 0, stream>>>(h, W1, a1s, a1d, z1h, es1x, ed1x);
    attn1_kernel<<<(NN * 16 + 255) / 256, 256, 0, stream>>>(row_ptr, csr16, z1h, es1x, ed1x, h1h);
    gemm2_kernel<<<gb, 256, 0, stream>>>(h1h, W2, a2s, a2d, z2h, es2x, ed2x);
    attn2_kernel<<<(NN * 4 + 255) / 256, 256, 0, stream>>>(row_ptr, csr16, z2h, es2x, ed2x, out);
}

// Round 10
// 200.815 us; speedup vs baseline: 2.2787x; 1.0831x over previous
//
#include <hip/hip_runtime.h>
#include <hip/hip_fp16.h>
#include <math.h>

#define NN 50000
#define EE 800000
#define FIN 128
#define F1  128   // HEADS*HID
#define NH  8
#define DH  16
#define F2  32
#define SLOPE 0.2f
#define LOG2E 1.44269504f

#define EB 4096                    // edges per block in S1/S3
#define NBLK ((EE + EB - 1) / EB)  // 196
#define BK  391                    // coarse buckets = ceil(NN/128)
#define SEGCAP 4096                // max edges per bucket segment (mean 2046)

typedef _Float16 f16x8 __attribute__((ext_vector_type(8)));
typedef float    f32x4 __attribute__((ext_vector_type(4)));

// ---------------- S1: coarse histogram ----------------
__global__ __launch_bounds__(256) void hist_kernel(const int* __restrict__ dst,
        int* __restrict__ hist) {
    __shared__ int lc[BK];
    int tid = threadIdx.x;
    for (int i = tid; i < BK; i += 256) lc[i] = 0;
    __syncthreads();
    int base = blockIdx.x * EB;
    int end = base + EB; if (end > EE) end = EE;
    for (int i = base + tid; i < end; i += 256)
        atomicAdd(&lc[dst[i] >> 7], 1);
    __syncthreads();
    for (int i = tid; i < BK; i += 256)
        if (lc[i]) atomicAdd(&hist[i], lc[i]);
}

// ---------------- S2: scan histogram -> segment bases + cursors ----------------
__global__ __launch_bounds__(256) void scan_hist_kernel(const int* __restrict__ hist,
        int* __restrict__ basea, int* __restrict__ cursor) {
    __shared__ int sh[256];
    int tid = threadIdx.x;
    int a0 = hist[2 * tid], a1 = hist[2 * tid + 1];   // hist zero-padded to 512
    int tsum = a0 + a1;
    sh[tid] = tsum;
    __syncthreads();
    for (int off = 1; off < 256; off <<= 1) {
        int t = (tid >= off) ? sh[tid - off] : 0;
        __syncthreads();
        sh[tid] += t;
        __syncthreads();
    }
    int ex = sh[tid] - tsum;
    basea[2 * tid] = ex;     cursor[2 * tid] = ex;
    basea[2 * tid + 1] = ex + a0; cursor[2 * tid + 1] = ex + a0;
}

// ---------------- S3: multisplit into bucket-sorted packed records ----------------
__global__ __launch_bounds__(256) void split_kernel(const int* __restrict__ src,
        const int* __restrict__ dst, int* __restrict__ cursor, unsigned int* __restrict__ sorted) {
    __shared__ int lc[512];
    __shared__ int lofs[512];
    __shared__ int lcur[BK];
    __shared__ int delta[BK];
    __shared__ int sh[256];
    __shared__ unsigned int recs[EB];   // 16 KB
    __shared__ unsigned short rbk[EB];  // 8 KB
    int tid = threadIdx.x;
    for (int i = tid; i < 512; i += 256) lc[i] = 0;
    __syncthreads();
    int base = blockIdx.x * EB;
    int cnt = EE - base; if (cnt > EB) cnt = EB;
    unsigned int myrec[16];
    #pragma unroll
    for (int k = 0; k < 16; ++k) {
        int i = base + tid + k * 256;
        myrec[k] = 0xFFFFFFFFu;
        if (i - base < cnt) {
            unsigned int d = (unsigned int)dst[i];
            myrec[k] = (d << 16) | (unsigned int)src[i];
            atomicAdd(&lc[d >> 7], 1);
        }
    }
    __syncthreads();
    int a0 = lc[2 * tid], a1 = lc[2 * tid + 1];
    int tsum = a0 + a1;
    sh[tid] = tsum;
    __syncthreads();
    for (int off = 1; off < 256; off <<= 1) {
        int t = (tid >= off) ? sh[tid - off] : 0;
        __syncthreads();
        sh[tid] += t;
        __syncthreads();
    }
    int ex = sh[tid] - tsum;
    lofs[2 * tid] = ex;
    lofs[2 * tid + 1] = ex + a0;
    __syncthreads();
    for (int b = tid; b < BK; b += 256) {
        int c = lc[b];
        lcur[b] = lofs[b];
        if (c) {
            int g = atomicAdd(&cursor[b], c);
            delta[b] = g - lofs[b];
        }
    }
    __syncthreads();
    #pragma unroll
    for (int k = 0; k < 16; ++k) {
        if (myrec[k] != 0xFFFFFFFFu) {
            int b = (int)(myrec[k] >> 23);      // dst >> 7
            int pos = atomicAdd(&lcur[b], 1);
            recs[pos] = myrec[k];
            rbk[pos] = (unsigned short)b;
        }
    }
    __syncthreads();
    for (int s = tid; s < cnt; s += 256)
        sorted[s + delta[rbk[s]]] = recs[s];
}

// ---------------- S4: per-bucket dense CSR build ----------------
__global__ __launch_bounds__(256) void csrbuild_kernel(const int* __restrict__ basea,
        const unsigned int* __restrict__ sorted, unsigned short* __restrict__ csr,
        int* __restrict__ row_ptr) {
    __shared__ unsigned int recs[SEGCAP];     // 16 KB
    __shared__ unsigned short csr_sh[SEGCAP]; // 8 KB
    __shared__ int ncnt[128], nofs[128], ncur[128];
    __shared__ int sh[256];
    int b = blockIdx.x;
    int tid = threadIdx.x;
    int s0 = basea[b], s1 = basea[b + 1];
    int cnt = s1 - s0; if (cnt > SEGCAP) cnt = SEGCAP;
    if (tid < 128) ncnt[tid] = 0;
    __syncthreads();
    for (int i = tid; i < cnt; i += 256) {
        unsigned int r = sorted[s0 + i];
        recs[i] = r;
        atomicAdd(&ncnt[(r >> 16) & 127], 1);
    }
    __syncthreads();
    int v = (tid < 128) ? ncnt[tid] : 0;
    sh[tid] = v;
    __syncthreads();
    for (int off = 1; off < 256; off <<= 1) {
        int t = (tid >= off) ? sh[tid - off] : 0;
        __syncthreads();
        sh[tid] += t;
        __syncthreads();
    }
    int ex = sh[tid] - v;
    if (tid < 128) {
        nofs[tid] = ex;
        ncur[tid] = ex;
        int node = b * 128 + tid;
        if (node < NN) row_ptr[node] = s0 + ex;
    }
    if (b == BK - 1 && tid == 0) row_ptr[NN] = EE;
    __syncthreads();
    for (int i = tid; i < cnt; i += 256) {
        unsigned int r = recs[i];
        int local = (r >> 16) & 127;
        int p = atomicAdd(&ncur[local], 1);
        csr_sh[p] = (unsigned short)(r & 0xFFFFu);
    }
    __syncthreads();
    for (int i = tid; i < cnt; i += 256)
        csr[s0 + i] = csr_sh[i];
}

// ---------------- prep: one-time W transposes to fp16 ----------------
// wt1[n*128+k] = W1[k*128+n]; wt2[n*128+k] = W2[k*32+n]
__global__ __launch_bounds__(256) void prep_kernel(const float* __restrict__ W1,
        const float* __restrict__ W2, __half* __restrict__ wt1, __half* __restrict__ wt2) {
    int tid = blockIdx.x * 256 + threadIdx.x;
    if (tid < FIN * F1) {
        int n = tid >> 7, k = tid & 127;
        wt1[tid] = __float2half(W1[k * F1 + n]);
    } else {
        int t2 = tid - FIN * F1;
        if (t2 < F2 * FIN) {
            int n = t2 >> 7, k = t2 & 127;
            wt2[t2] = __float2half(W2[k * F2 + n]);
        }
    }
}

// ---------------- GEMM1 (MFMA fp16) + fp32 es/ed epilogue ----------------
__global__ __launch_bounds__(256) void gemm1_kernel(const float* __restrict__ h,
        const __half* __restrict__ wt1, const float* __restrict__ a1s, const float* __restrict__ a1d,
        __half* __restrict__ z1h, float* __restrict__ es1x, float* __restrict__ ed1x) {
    __shared__ alignas(16) __half hs[64 * 136];     // 17.4 KB
    __shared__ alignas(16) __half wls[128 * 136];   // 34.8 KB
    int tid = threadIdx.x;
    // stage W1^T fp16 via b128 copies (pre-transposed in global)
    for (int c = tid; c < 2048; c += 256) {         // 16-B chunks
        int row = c >> 4, ch = c & 15;
        *(float4*)&wls[row * 136 + ch * 8] = *(const float4*)&wt1[row * 128 + ch * 8];
    }
    int rowBase = blockIdx.x * 64;
    for (int idx4 = tid; idx4 < 64 * 32; idx4 += 256) {
        int r = idx4 >> 5, cc = (idx4 & 31) * 4;
        int n = rowBase + r;
        float4 v = (n < NN) ? *(const float4*)&h[(size_t)n * FIN + cc] : make_float4(0, 0, 0, 0);
        union { __half2 h2[2]; int2 i; } u;
        u.h2[0] = __floats2half2_rn(v.x, v.y);
        u.h2[1] = __floats2half2_rn(v.z, v.w);
        *(int2*)&hs[r * 136 + cc] = u.i;
    }
    __syncthreads();
    int l = tid & 63, w = tid >> 6;
    int q = l >> 4, cl = l & 15;
    int m0 = w * 16;
    float as[8], ad[8];
    #pragma unroll
    for (int t = 0; t < 8; ++t) { as[t] = a1s[t * DH + cl]; ad[t] = a1d[t * DH + cl]; }
    f32x4 acc[8];
    #pragma unroll
    for (int t = 0; t < 8; ++t) acc[t] = (f32x4){0.f, 0.f, 0.f, 0.f};
    const __half* ap = &hs[(m0 + cl) * 136 + q * 8];
    const __half* bp = &wls[cl * 136 + q * 8];
    #pragma unroll
    for (int k0 = 0; k0 < 128; k0 += 32) {
        f16x8 af = *(const f16x8*)(ap + k0);
        #pragma unroll
        for (int t = 0; t < 8; ++t) {
            f16x8 bf = *(const f16x8*)(bp + t * 16 * 136 + k0);
            acc[t] = __builtin_amdgcn_mfma_f32_16x16x32_f16(af, bf, acc[t], 0, 0, 0);
        }
    }
    #pragma unroll
    for (int t = 0; t < 8; ++t) {
        #pragma unroll
        for (int reg = 0; reg < 4; ++reg) {
            int row = rowBase + m0 + q * 4 + reg;
            float z = acc[t][reg];
            float s = z * as[t], d = z * ad[t];
            s += __shfl_xor(s, 1, 64); d += __shfl_xor(d, 1, 64);
            s += __shfl_xor(s, 2, 64); d += __shfl_xor(d, 2, 64);
            s += __shfl_xor(s, 4, 64); d += __shfl_xor(d, 4, 64);
            s += __shfl_xor(s, 8, 64); d += __shfl_xor(d, 8, 64);
            if (row < NN) {
                z1h[(size_t)row * F1 + t * 16 + cl] = __float2half(z);
                if (cl == 0) {
                    es1x[row * NH + t] = s * LOG2E;
                    ed1x[row * NH + t] = d * LOG2E;
                }
            }
        }
    }
}

// ---------------- GEMM2 (MFMA fp16) + fp32 es/ed epilogue ----------------
__global__ __launch_bounds__(256) void gemm2_kernel(const __half* __restrict__ h1h,
        const __half* __restrict__ wt2, const float* __restrict__ a2s, const float* __restrict__ a2d,
        __half* __restrict__ z2h, float* __restrict__ es2x, float* __restrict__ ed2x) {
    __shared__ alignas(16) __half hs[64 * 136];    // 17.4 KB
    __shared__ alignas(16) __half wls[32 * 136];   // 8.7 KB
    int tid = threadIdx.x;
    for (int c = tid; c < 512; c += 256) {
        int row = c >> 4, ch = c & 15;
        *(float4*)&wls[row * 136 + ch * 8] = *(const float4*)&wt2[row * 128 + ch * 8];
    }
    int rowBase = blockIdx.x * 64;
    for (int idx8 = tid; idx8 < 64 * 16; idx8 += 256) {
        int r = idx8 >> 4, cc = (idx8 & 15) * 8;
        int n = rowBase + r;
        float4 v = make_float4(0, 0, 0, 0);
        if (n < NN) v = *(const float4*)&h1h[(size_t)n * FIN + cc];
        *(float4*)&hs[r * 136 + cc] = v;
    }
    __syncthreads();
    int l = tid & 63, w = tid >> 6;
    int q = l >> 4, cl = l & 15;
    int m0 = w * 16;
    float as0 = a2s[cl], as1 = a2s[16 + cl];
    float ad0 = a2d[cl], ad1 = a2d[16 + cl];
    f32x4 acc[2];
    acc[0] = (f32x4){0.f, 0.f, 0.f, 0.f};
    acc[1] = (f32x4){0.f, 0.f, 0.f, 0.f};
    const __half* ap = &hs[(m0 + cl) * 136 + q * 8];
    const __half* bp = &wls[cl * 136 + q * 8];
    #pragma unroll
    for (int k0 = 0; k0 < 128; k0 += 32) {
        f16x8 af = *(const f16x8*)(ap + k0);
        #pragma unroll
        for (int t = 0; t < 2; ++t) {
            f16x8 bf = *(const f16x8*)(bp + t * 16 * 136 + k0);
            acc[t] = __builtin_amdgcn_mfma_f32_16x16x32_f16(af, bf, acc[t], 0, 0, 0);
        }
    }
    #pragma unroll
    for (int reg = 0; reg < 4; ++reg) {
        int row = rowBase + m0 + q * 4 + reg;
        float s = acc[0][reg] * as0 + acc[1][reg] * as1;
        float d = acc[0][reg] * ad0 + acc[1][reg] * ad1;
        s += __shfl_xor(s, 1, 64); d += __shfl_xor(d, 1, 64);
        s += __shfl_xor(s, 2, 64); d += __shfl_xor(d, 2, 64);
        s += __shfl_xor(s, 4, 64); d += __shfl_xor(d, 4, 64);
        s += __shfl_xor(s, 8, 64); d += __shfl_xor(d, 8, 64);
        if (row < NN) {
            z2h[(size_t)row * F2 + cl]      = __float2half(acc[0][reg]);
            z2h[(size_t)row * F2 + 16 + cl] = __float2half(acc[1][reg]);
            if (cl == 0) {
                es2x[row] = s * LOG2E;
                ed2x[row] = d * LOG2E;
            }
        }
    }
}

// ---------------- attention layer 1: 16 lanes per node, 4-wide unrolled ----------------
__global__ __launch_bounds__(256) void attn1_kernel(const int* __restrict__ row_ptr,
        const unsigned short* __restrict__ csr, const __half* __restrict__ z1h,
        const float* __restrict__ es, const float* __restrict__ ed,
        __half* __restrict__ h1h) {
    int gt = blockIdx.x * 256 + threadIdx.x;
    int n = gt >> 4;          // node
    int j = gt & 15;          // dim-group lane
    int hl = j >> 1;          // head
    if (n >= NN) return;
    int b0 = row_ptr[n];
    int cnt = row_ptr[n + 1] - b0;
    float edn = ed[n * NH + hl];
    float acc[8] = {0.f, 0.f, 0.f, 0.f, 0.f, 0.f, 0.f, 0.f};
    float ws = 0.f;
    int i = 0;
    for (; i + 4 <= cnt; i += 4) {
        int s0 = csr[b0 + i], s1 = csr[b0 + i + 1], s2 = csr[b0 + i + 2], s3 = csr[b0 + i + 3];
        float e0 = es[s0 * NH + hl] + edn;
        float e1 = es[s1 * NH + hl] + edn;
        float e2 = es[s2 * NH + hl] + edn;
        float e3 = es[s3 * NH + hl] + edn;
        union { float4 f; __half2 h2[4]; } u0, u1, u2, u3;
        u0.f = *(const float4*)&z1h[(size_t)s0 * F1 + j * 8];
        u1.f = *(const float4*)&z1h[(size_t)s1 * F1 + j * 8];
        u2.f = *(const float4*)&z1h[(size_t)s2 * F1 + j * 8];
        u3.f = *(const float4*)&z1h[(size_t)s3 * F1 + j * 8];
        float w0 = exp2f(e0 >= 0.f ? e0 : SLOPE * e0);
        float w1 = exp2f(e1 >= 0.f ? e1 : SLOPE * e1);
        float w2 = exp2f(e2 >= 0.f ? e2 : SLOPE * e2);
        float w3 = exp2f(e3 >= 0.f ? e3 : SLOPE * e3);
        ws += (w0 + w1) + (w2 + w3);
        #pragma unroll
        for (int t = 0; t < 4; ++t) {
            float2 v0 = __half22float2(u0.h2[t]);
            float2 v1 = __half22float2(u1.h2[t]);
            float2 v2 = __half22float2(u2.h2[t]);
            float2 v3 = __half22float2(u3.h2[t]);
            acc[2*t]   = fmaf(w0, v0.x, fmaf(w1, v1.x, fmaf(w2, v2.x, fmaf(w3, v3.x, acc[2*t]))));
            acc[2*t+1] = fmaf(w0, v0.y, fmaf(w1, v1.y, fmaf(w2, v2.y, fmaf(w3, v3.y, acc[2*t+1]))));
        }
    }
    for (; i < cnt; ++i) {
        int s = csr[b0 + i];
        float e = es[s * NH + hl] + edn;
        float wv = exp2f(e >= 0.f ? e : SLOPE * e);
        ws += wv;
        union { float4 f; __half2 h2[4]; } u;
        u.f = *(const float4*)&z1h[(size_t)s * F1 + j * 8];
        #pragma unroll
        for (int t = 0; t < 4; ++t) {
            float2 v = __half22float2(u.h2[t]);
            acc[2*t]   = fmaf(wv, v.x, acc[2*t]);
            acc[2*t+1] = fmaf(wv, v.y, acc[2*t+1]);
        }
    }
    float rs = ws > 0.f ? 1.0f / ws : 0.f;
    union { float4 f; __half2 h2[4]; } p;
    #pragma unroll
    for (int t = 0; t < 4; ++t) {
        float x0 = acc[2*t] * rs, x1 = acc[2*t+1] * rs;
        x0 = x0 > 0.f ? x0 : __expf(x0) - 1.0f;   // ELU
        x1 = x1 > 0.f ? x1 : __expf(x1) - 1.0f;
        p.h2[t] = __floats2half2_rn(x0, x1);
    }
    *(float4*)&h1h[(size_t)n * F1 + j * 8] = p.f;
}

// ---------------- attention layer 2: 4 lanes per node, 4-wide unrolled ----------------
__global__ __launch_bounds__(256) void attn2_kernel(const int* __restrict__ row_ptr,
        const unsigned short* __restrict__ csr, const __half* __restrict__ z2h,
        const float* __restrict__ es, const float* __restrict__ ed,
        float* __restrict__ out) {
    int gt = blockIdx.x * 256 + threadIdx.x;
    int n = gt >> 2;          // node
    int j = gt & 3;           // dims [8j, 8j+8)
    if (n >= NN) return;
    int b0 = row_ptr[n];
    int cnt = row_ptr[n + 1] - b0;
    float edn = ed[n];
    float acc[8] = {0.f, 0.f, 0.f, 0.f, 0.f, 0.f, 0.f, 0.f};
    float ws = 0.f;
    int i = 0;
    for (; i + 4 <= cnt; i += 4) {
        int s0 = csr[b0 + i], s1 = csr[b0 + i + 1], s2 = csr[b0 + i + 2], s3 = csr[b0 + i + 3];
        float e0 = es[s0] + edn;
        float e1 = es[s1] + edn;
        float e2 = es[s2] + edn;
        float e3 = es[s3] + edn;
        union { float4 f; __half2 h2[4]; } u0, u1, u2, u3;
        u0.f = *(const float4*)&z2h[(size_t)s0 * F2 + j * 8];
        u1.f = *(const float4*)&z2h[(size_t)s1 * F2 + j * 8];
        u2.f = *(const float4*)&z2h[(size_t)s2 * F2 + j * 8];
        u3.f = *(const float4*)&z2h[(size_t)s3 * F2 + j * 8];
        float w0 = exp2f(e0 >= 0.f ? e0 : SLOPE * e0);
        float w1 = exp2f(e1 >= 0.f ? e1 : SLOPE * e1);
        float w2 = exp2f(e2 >= 0.f ? e2 : SLOPE * e2);
        float w3 = exp2f(e3 >= 0.f ? e3 : SLOPE * e3);
        ws += (w0 + w1) + (w2 + w3);
        #pragma unroll
        for (int t = 0; t < 4; ++t) {
            float2 v0 = __half22float2(u0.h2[t]);
            float2 v1 = __half22float2(u1.h2[t]);
            float2 v2 = __half22float2(u2.h2[t]);
            float2 v3 = __half22float2(u3.h2[t]);
            acc[2*t]   = fmaf(w0, v0.x, fmaf(w1, v1.x, fmaf(w2, v2.x, fmaf(w3, v3.x, acc[2*t]))));
            acc[2*t+1] = fmaf(w0, v0.y, fmaf(w1, v1.y, fmaf(w2, v2.y, fmaf(w3, v3.y, acc[2*t+1]))));
        }
    }
    for (; i < cnt; ++i) {
        int s = csr[b0 + i];
        float e = es[s] + edn;
        float wv = exp2f(e >= 0.f ? e : SLOPE * e);
        ws += wv;
        union { float4 f; __half2 h2[4]; } u;
        u.f = *(const float4*)&z2h[(size_t)s * F2 + j * 8];
        #pragma unroll
        for (int t = 0; t < 4; ++t) {
            float2 v = __half22float2(u.h2[t]);
            acc[2*t]   = fmaf(wv, v.x, acc[2*t]);
            acc[2*t+1] = fmaf(wv, v.y, acc[2*t+1]);
        }
    }
    float rs = ws > 0.f ? 1.0f / ws : 0.f;
    float* op = &out[(size_t)n * F2 + j * 8];
    *(float4*)&op[0] = make_float4(acc[0]*rs, acc[1]*rs, acc[2]*rs, acc[3]*rs);
    *(float4*)&op[4] = make_float4(acc[4]*rs, acc[5]*rs, acc[6]*rs, acc[7]*rs);
}

extern "C" void kernel_launch(void* const* d_in, const int* in_sizes, int n_in,
                              void* d_out, int out_size, void* d_ws, size_t ws_size,
                              hipStream_t stream) {
    const float* h   = (const float*)d_in[0];
    const float* W1  = (const float*)d_in[1];
    const float* a1s = (const float*)d_in[2];
    const float* a1d = (const float*)d_in[3];
    const float* W2  = (const float*)d_in[4];
    const float* a2s = (const float*)d_in[5];
    const float* a2d = (const float*)d_in[6];
    const int*   src = (const int*)d_in[7];
    const int*   dst = (const int*)d_in[8];
    float* out = (float*)d_out;

    // workspace layout (4-byte units, fp regions 16B-aligned)
    int* ip      = (int*)d_ws;
    int* hist    = ip;                       // 512 (zeroed; only [0,BK) used)
    int* basea   = hist + 512;               // 520
    int* cursor  = basea + 520;              // 512
    int* row_ptr = cursor + 512;             // NN+1 -> pad to NN+8
    unsigned int* sorted = (unsigned int*)(row_ptr + NN + 8);  // EE
    unsigned short* csr16 = (unsigned short*)(sorted + EE);    // EE ushorts
    float* es1x = (float*)(csr16 + EE);      // NN*8
    float* ed1x = es1x + (size_t)NN * NH;    // NN*8
    float* es2x = ed1x + (size_t)NN * NH;    // NN
    float* ed2x = es2x + NN;                 // NN
    __half* z1h = (__half*)(ed2x + NN);      // NN*128
    __half* h1h = z1h + (size_t)NN * F1;     // NN*128
    __half* z2h = h1h + (size_t)NN * F1;     // NN*32
    __half* wt1 = z2h + (size_t)NN * F2;     // 128*128
    __half* wt2 = wt1 + FIN * F1;            // 32*128

    hipMemsetAsync(hist, 0, 512 * sizeof(int), stream);

    prep_kernel<<<(FIN * F1 + F2 * FIN + 255) / 256, 256, 0, stream>>>(W1, W2, wt1, wt2);
    hist_kernel<<<NBLK, 256, 0, stream>>>(dst, hist);
    scan_hist_kernel<<<1, 256, 0, stream>>>(hist, basea, cursor);
    split_kernel<<<NBLK, 256, 0, stream>>>(src, dst, cursor, sorted);
    csrbuild_kernel<<<BK, 256, 0, stream>>>(basea, sorted, csr16, row_ptr);

    int gb = (NN + 63) / 64;
    gemm1_kernel<<<gb, 256, 0, stream>>>(h, wt1, a1s, a1d, z1h, es1x, ed1x);
    attn1_kernel<<<(NN * 16 + 255) / 256, 256, 0, stream>>>(row_ptr, csr16, z1h, es1x, ed1x, h1h);
    gemm2_kernel<<<gb, 256, 0, stream>>>(h1h, wt2, a2s, a2d, z2h, es2x, ed2x);
    attn2_kernel<<<(NN * 4 + 255) / 256, 256, 0, stream>>>(row_ptr, csr16, z2h, es2x, ed2x, out);
}